// Round 2
// baseline (372.886 us; speedup 1.0000x reference)
//
#include <hip/hip_runtime.h>

#define BLOCK 256
#define GRID  2048
#define NGRAPH 8

// d_ws layout: float[0..7] = per-graph dots, float[8] = base, int @ float[9] = block counter

__global__ __launch_bounds__(BLOCK) void reduce_kernel(
    const float4* __restrict__ x4,
    const float4* __restrict__ t4,
    const int*    __restrict__ batch,
    float* __restrict__ g_acc,
    int*   __restrict__ d_count,
    float* __restrict__ out,
    long long M /* = N*4 float4 elements */)
{
    __shared__ float s_dots[NGRAPH];
    __shared__ float s_base;
    __shared__ int   s_last;
    const int tid = threadIdx.x;
    if (tid < NGRAPH) s_dots[tid] = 0.0f;
    if (tid == 0)     s_base = 0.0f;
    __syncthreads();

    // Contiguous slab per block (batch is sorted -> lane's graph id is
    // near-constant across its iterations; flush-on-change is ~free).
    const long long chunk =
        ((M + (long long)GRID * BLOCK - 1) / ((long long)GRID * BLOCK)) * BLOCK;
    long long s0 = (long long)blockIdx.x * chunk;
    long long s1 = s0 + chunk;
    if (s1 > M) s1 = M;

    float base  = 0.0f;
    float d_acc = 0.0f;
    int   b_cur = 0;
    if (s0 + tid < M) b_cur = batch[(s0 + tid) >> 2];

    #pragma unroll 4
    for (long long e = s0 + tid; e < s1; e += BLOCK) {
        float4 a = x4[e];
        float4 c = t4[e];
        int b = batch[e >> 2];   // 4 float4 elements per row (F=16)
        base += a.x*a.x + a.y*a.y + a.z*a.z + a.w*a.w
              + c.x*c.x + c.y*c.y + c.z*c.z + c.w*c.w;
        float d = a.x*c.x + a.y*c.y + a.z*c.z + a.w*c.w;
        if (b != b_cur) {                 // rare: only at segment boundaries
            atomicAdd(&s_dots[b_cur], d_acc);
            d_acc = 0.0f;
            b_cur = b;
        }
        d_acc += d;
    }
    atomicAdd(&s_dots[b_cur], d_acc);     // final flush (adds 0 if idle block)

    // block-reduce base: wave butterfly, one LDS atomic per wave
    for (int off = 32; off > 0; off >>= 1)
        base += __shfl_xor(base, off, 64);
    if ((tid & 63) == 0)
        atomicAdd(&s_base, base);
    __syncthreads();

    if (tid < NGRAPH) atomicAdd(&g_acc[tid], s_dots[tid]);
    if (tid == 0)     atomicAdd(&g_acc[NGRAPH], s_base);

    // fused finalize: last block to finish computes the output
    if (tid == 0) {
        __threadfence();                          // make our atomics visible
        int prev = atomicAdd(d_count, 1);         // device-scope by default
        s_last = (prev == GRID - 1) ? 1 : 0;
    }
    __syncthreads();
    if (tid == 0 && s_last) {
        __threadfence();                          // acquire side
        float s = 0.0f;
        #pragma unroll
        for (int i = 0; i < NGRAPH; ++i) {
            float v = __hip_atomic_load(&g_acc[i], __ATOMIC_RELAXED,
                                        __HIP_MEMORY_SCOPE_AGENT);
            s += fabsf(v);
        }
        float bs = __hip_atomic_load(&g_acc[NGRAPH], __ATOMIC_RELAXED,
                                     __HIP_MEMORY_SCOPE_AGENT);
        out[0] = bs - 2.0f * s;
    }
}

extern "C" void kernel_launch(void* const* d_in, const int* in_sizes, int n_in,
                              void* d_out, int out_size, void* d_ws, size_t ws_size,
                              hipStream_t stream) {
    const float* inp   = (const float*)d_in[0];
    const float* tgt   = (const float*)d_in[1];
    const int*   batch = (const int*)d_in[2];

    const long long Nrows = (long long)in_sizes[0] / 16;  // F = 16
    const long long M     = Nrows * 4;                    // float4 elements

    float* g_acc   = (float*)d_ws;
    int*   d_count = (int*)((float*)d_ws + NGRAPH + 1);
    hipMemsetAsync(d_ws, 0, (NGRAPH + 1) * sizeof(float) + sizeof(int), stream);

    reduce_kernel<<<GRID, BLOCK, 0, stream>>>(
        (const float4*)inp, (const float4*)tgt, batch, g_acc, d_count,
        (float*)d_out, M);
}

// Round 3
// 370.421 us; speedup vs baseline: 1.0067x; 1.0067x over previous
//
#include <hip/hip_runtime.h>

#define BLOCK 256
#define GRID  2048
#define NGRAPH 8

__device__ __forceinline__ float dot4(const float4 a, const float4 b) {
    return a.x*b.x + a.y*b.y + a.z*b.z + a.w*b.w;
}

// d_ws: float[0..7]=dots, float[8]=base, int @ float[9]=block counter

__global__ __launch_bounds__(BLOCK) void reduce_kernel(
    const float4* __restrict__ x4,
    const float4* __restrict__ t4,
    const int*    __restrict__ batch,
    float* __restrict__ g_acc,
    int*   __restrict__ d_count,
    float* __restrict__ out,
    long long Nrows)
{
    __shared__ float s_dots[NGRAPH];
    __shared__ float s_base;
    __shared__ int   s_last;
    const int tid = threadIdx.x;
    if (tid < NGRAPH) s_dots[tid] = 0.0f;
    if (tid == 0)     s_base = 0.0f;
    __syncthreads();

    const long long stride = (long long)GRID * BLOCK;   // threads in grid
    long long r = (long long)blockIdx.x * BLOCK + tid;  // row index (F=16 floats)
    const long long nfull = Nrows / stride;             // uniform trip count

    float acc[NGRAPH];
    #pragma unroll
    for (int g = 0; g < NGRAPH; ++g) acc[g] = 0.0f;
    float base = 0.0f;

    // Hot loop: branch-free body, 9 independent loads/iter, no cross-lane ops.
    for (long long k = 0; k < nfull; ++k, r += stride) {
        const long long r4 = r << 2;
        float4 a0 = x4[r4+0], a1 = x4[r4+1], a2 = x4[r4+2], a3 = x4[r4+3];
        float4 c0 = t4[r4+0], c1 = t4[r4+1], c2 = t4[r4+2], c3 = t4[r4+3];
        int b = batch[r];
        base += dot4(a0,a0) + dot4(a1,a1) + dot4(a2,a2) + dot4(a3,a3)
              + dot4(c0,c0) + dot4(c1,c1) + dot4(c2,c2) + dot4(c3,c3);
        float d = dot4(a0,c0) + dot4(a1,c1) + dot4(a2,c2) + dot4(a3,c3);
        #pragma unroll
        for (int g = 0; g < NGRAPH; ++g)
            acc[g] += (b == g) ? d : 0.0f;   // if-converted: cmp+cndmask+add
    }
    // guarded tail (at most one iteration per thread)
    if (r < Nrows) {
        const long long r4 = r << 2;
        float4 a0 = x4[r4+0], a1 = x4[r4+1], a2 = x4[r4+2], a3 = x4[r4+3];
        float4 c0 = t4[r4+0], c1 = t4[r4+1], c2 = t4[r4+2], c3 = t4[r4+3];
        int b = batch[r];
        base += dot4(a0,a0) + dot4(a1,a1) + dot4(a2,a2) + dot4(a3,a3)
              + dot4(c0,c0) + dot4(c1,c1) + dot4(c2,c2) + dot4(c3,c3);
        float d = dot4(a0,c0) + dot4(a1,c1) + dot4(a2,c2) + dot4(a3,c3);
        #pragma unroll
        for (int g = 0; g < NGRAPH; ++g)
            acc[g] += (b == g) ? d : 0.0f;
    }

    // once-per-block reduction: wave butterfly over 9 values
    #pragma unroll
    for (int off = 32; off > 0; off >>= 1) {
        base += __shfl_xor(base, off, 64);
        #pragma unroll
        for (int g = 0; g < NGRAPH; ++g)
            acc[g] += __shfl_xor(acc[g], off, 64);
    }
    if ((tid & 63) == 0) {
        #pragma unroll
        for (int g = 0; g < NGRAPH; ++g)
            atomicAdd(&s_dots[g], acc[g]);
        atomicAdd(&s_base, base);
    }
    __syncthreads();

    if (tid < NGRAPH) atomicAdd(&g_acc[tid], s_dots[tid]);
    if (tid == 0)     atomicAdd(&g_acc[NGRAPH], s_base);

    // fused finalize: last block computes the scalar output
    if (tid == 0) {
        __threadfence();
        int prev = atomicAdd(d_count, 1);
        s_last = (prev == GRID - 1) ? 1 : 0;
    }
    __syncthreads();
    if (tid == 0 && s_last) {
        __threadfence();
        float s = 0.0f;
        #pragma unroll
        for (int i = 0; i < NGRAPH; ++i) {
            float v = __hip_atomic_load(&g_acc[i], __ATOMIC_RELAXED,
                                        __HIP_MEMORY_SCOPE_AGENT);
            s += fabsf(v);
        }
        float bs = __hip_atomic_load(&g_acc[NGRAPH], __ATOMIC_RELAXED,
                                     __HIP_MEMORY_SCOPE_AGENT);
        out[0] = bs - 2.0f * s;
    }
}

extern "C" void kernel_launch(void* const* d_in, const int* in_sizes, int n_in,
                              void* d_out, int out_size, void* d_ws, size_t ws_size,
                              hipStream_t stream) {
    const float* inp   = (const float*)d_in[0];
    const float* tgt   = (const float*)d_in[1];
    const int*   batch = (const int*)d_in[2];

    const long long Nrows = (long long)in_sizes[0] / 16;  // F = 16

    float* g_acc   = (float*)d_ws;
    int*   d_count = (int*)((float*)d_ws + NGRAPH + 1);
    hipMemsetAsync(d_ws, 0, (NGRAPH + 1) * sizeof(float) + sizeof(int), stream);

    reduce_kernel<<<GRID, BLOCK, 0, stream>>>(
        (const float4*)inp, (const float4*)tgt, batch, g_acc, d_count,
        (float*)d_out, Nrows);
}